// Round 1
// baseline (180.434 us; speedup 1.0000x reference)
//
#include <hip/hip_runtime.h>

#define FEPS 1e-8f

// Order-isomorphic to atan2(y, x) (monotone in angle, same +/-pi cut).
__device__ __forceinline__ float pseudo_angle(float x, float y) {
    float d = fabsf(x) + fabsf(y);
    float q = x / fmaxf(d, 1e-38f);
    return copysignf(1.0f - q, y);
}

__global__ __launch_bounds__(256) void riou_kernel(
    const float* __restrict__ pred, const float* __restrict__ target,
    const int* __restrict__ pos_idx, float* __restrict__ out,
    double* __restrict__ ws_num, int* __restrict__ ws_den, int n)
{
    int gid = blockIdx.x * blockDim.x + threadIdx.x;
    float lnum = 0.0f;
    int   lden = 0;

    if (gid < n) {
        const float DEG = 0.017453292519943295f;
        // box1 = pred, box2 = target
        float p0 = pred[gid*5+0], p1 = pred[gid*5+1], p2 = pred[gid*5+2],
              p3 = pred[gid*5+3], p4 = pred[gid*5+4];
        float t0 = target[gid*5+0], t1 = target[gid*5+1], t2 = target[gid*5+2],
              t3 = target[gid*5+3], t4 = target[gid*5+4];

        float a1 = p4 * DEG;                       // deg2rad(pred_angle)
        float a2 = (t4 * 180.0f - 180.0f) * DEG;   // deg2rad(target*180-180)

        float s1, c1_; sincosf(a1, &s1, &c1_);
        float s2, c2_; sincosf(a2, &s2, &c2_);

        const float SXc[4] = {0.5f, -0.5f, -0.5f, 0.5f};
        const float SYc[4] = {0.5f, 0.5f, -0.5f, -0.5f};
        float c1x[4], c1y[4], c2x[4], c2y[4];
        #pragma unroll
        for (int k = 0; k < 4; ++k) {
            float xs = SXc[k] * p2, ys = SYc[k] * p3;
            c1x[k] = xs * c1_ - ys * s1 + p0;
            c1y[k] = xs * s1 + ys * c1_ + p1;
            float xs2 = SXc[k] * t2, ys2 = SYc[k] * t3;
            c2x[k] = xs2 * c2_ - ys2 * s2 + t0;
            c2y[k] = xs2 * s2 + ys2 * c2_ + t1;
        }

        float vx[24], vy[24], ang[24];
        bool  valid[24];

        // --- box_in_box: c1 corners in box2 -> valid[0..3]
        {
            float ax = c2x[0], ay = c2y[0];
            float abx = c2x[1] - ax, aby = c2y[1] - ay;
            float adx = c2x[3] - ax, ady = c2y[3] - ay;
            float iab = 1.0f / (abx*abx + aby*aby + FEPS);
            float iad = 1.0f / (adx*adx + ady*ady + FEPS);
            #pragma unroll
            for (int k = 0; k < 4; ++k) {
                float amx = c1x[k] - ax, amy = c1y[k] - ay;
                float pab = (abx*amx + aby*amy) * iab;
                float pad_ = (adx*amx + ady*amy) * iad;
                valid[k] = (pab > -1e-6f) && (pab < 1.0f + 1e-6f) &&
                           (pad_ > -1e-6f) && (pad_ < 1.0f + 1e-6f);
                vx[k] = c1x[k]; vy[k] = c1y[k];
            }
        }
        // --- box_in_box: c2 corners in box1 -> valid[4..7]
        {
            float ax = c1x[0], ay = c1y[0];
            float abx = c1x[1] - ax, aby = c1y[1] - ay;
            float adx = c1x[3] - ax, ady = c1y[3] - ay;
            float iab = 1.0f / (abx*abx + aby*aby + FEPS);
            float iad = 1.0f / (adx*adx + ady*ady + FEPS);
            #pragma unroll
            for (int k = 0; k < 4; ++k) {
                float amx = c2x[k] - ax, amy = c2y[k] - ay;
                float pab = (abx*amx + aby*amy) * iab;
                float pad_ = (adx*amx + ady*amy) * iad;
                valid[4+k] = (pab > -1e-6f) && (pab < 1.0f + 1e-6f) &&
                             (pad_ > -1e-6f) && (pad_ < 1.0f + 1e-6f);
                vx[4+k] = c2x[k]; vy[4+k] = c2y[k];
            }
        }
        // --- edge intersections -> valid[8..23]
        #pragma unroll
        for (int i = 0; i < 4; ++i) {
            float px = c1x[i], py = c1y[i];
            float rx = c1x[(i+1)&3] - px, ry = c1y[(i+1)&3] - py;
            #pragma unroll
            for (int j = 0; j < 4; ++j) {
                float qx = c2x[j], qy = c2y[j];
                float sx = c2x[(j+1)&3] - qx, sy = c2y[(j+1)&3] - qy;
                float rxs = rx*sy - ry*sx;
                float qpx = qx - px, qpy = qy - py;
                float inv = 1.0f / (rxs + FEPS);
                float tt = (qpx*sy - qpy*sx) * inv;
                float uu = (qpx*ry - qpy*rx) * inv;
                bool mk = (tt > 0.0f) && (tt < 1.0f) && (uu > 0.0f) && (uu < 1.0f);
                int idx = 8 + i*4 + j;
                valid[idx] = mk;
                vx[idx] = mk ? (px + tt*rx) : 0.0f;
                vy[idx] = mk ? (py + tt*ry) : 0.0f;
            }
        }

        // --- convex_area
        float sumx = 0.0f, sumy = 0.0f; int nv = 0;
        #pragma unroll
        for (int i = 0; i < 24; ++i) {
            float m = valid[i] ? 1.0f : 0.0f;
            sumx += vx[i] * m; sumy += vy[i] * m;
            nv += valid[i] ? 1 : 0;
        }
        float invn = 1.0f / fmaxf((float)nv, 1.0f);
        float mx = sumx * invn, my = sumy * invn;

        #pragma unroll
        for (int i = 0; i < 24; ++i) {
            float dx = vx[i] - mx, dy = vy[i] - my;
            vx[i] = dx; vy[i] = dy;
            ang[i] = valid[i] ? pseudo_angle(dx, dy) : 1e9f;
        }

        // odd-even transposition sort (stable: strict <), fully unrolled
        #pragma unroll
        for (int ph = 0; ph < 24; ++ph) {
            #pragma unroll
            for (int i = (ph & 1); i < 23; i += 2) {
                float a0 = ang[i], a1v = ang[i+1];
                bool sw = a1v < a0;
                ang[i]   = sw ? a1v : a0;
                ang[i+1] = sw ? a0  : a1v;
                float x0 = vx[i], x1 = vx[i+1];
                vx[i]   = sw ? x1 : x0;
                vx[i+1] = sw ? x0 : x1;
                float y0 = vy[i], y1 = vy[i+1];
                vy[i]   = sw ? y1 : y0;
                vy[i+1] = sw ? y0 : y1;
            }
        }

        // shoelace with invalid -> first-sorted-vertex substitution
        float v0x = vx[0], v0y = vy[0];
        float cs = 0.0f;
        #pragma unroll
        for (int i = 0; i < 24; ++i) {
            int j = (i + 1) % 24;
            float xi = (ang[i] < 1e8f) ? vx[i] : v0x;
            float yi = (ang[i] < 1e8f) ? vy[i] : v0y;
            float xj = (ang[j] < 1e8f) ? vx[j] : v0x;
            float yj = (ang[j] < 1e8f) ? vy[j] : v0y;
            cs += xi * yj - yi * xj;
        }
        float inter = (nv >= 3) ? (0.5f * fabsf(cs)) : 0.0f;

        float area1 = p2 * p3;
        float area2 = t2 * t3;
        float uni = area1 + area2 - inter;
        float iou = inter / (uni + FEPS);
        iou = fminf(fmaxf(iou, 1e-7f), 1.0f - 1e-7f);

        out[1 + gid] = iou;

        int m = (pos_idx[gid] != 0) ? 1 : 0;
        lnum = (1.0f - iou) * (float)m;
        lden = m;
    }

    // --- block reduction for the loss
    #pragma unroll
    for (int off = 32; off > 0; off >>= 1) {
        lnum += __shfl_down(lnum, off);
        lden += __shfl_down(lden, off);
    }
    __shared__ float snum[4];
    __shared__ int   sden[4];
    int wave = threadIdx.x >> 6, lane = threadIdx.x & 63;
    if (lane == 0) { snum[wave] = lnum; sden[wave] = lden; }
    __syncthreads();
    if (threadIdx.x == 0) {
        float bn = snum[0] + snum[1] + snum[2] + snum[3];
        int   bd = sden[0] + sden[1] + sden[2] + sden[3];
        atomicAdd(ws_num, (double)bn);
        atomicAdd(ws_den, bd);
    }
}

__global__ void riou_finalize(const double* __restrict__ ws_num,
                              const int* __restrict__ ws_den,
                              float* __restrict__ out)
{
    double den = (double)max(ws_den[0], 1);
    out[0] = (float)(ws_num[0] / den);
}

extern "C" void kernel_launch(void* const* d_in, const int* in_sizes, int n_in,
                              void* d_out, int out_size, void* d_ws, size_t ws_size,
                              hipStream_t stream) {
    const float* pred   = (const float*)d_in[0];
    const float* target = (const float*)d_in[1];
    const int*   posidx = (const int*)d_in[2];   // bool -> int per harness convention
    float* out = (float*)d_out;

    int n = in_sizes[0] / 5;

    double* ws_num = (double*)d_ws;
    int*    ws_den = (int*)((char*)d_ws + 8);
    hipMemsetAsync(d_ws, 0, 16, stream);

    int block = 256;
    int grid = (n + block - 1) / block;
    riou_kernel<<<grid, block, 0, stream>>>(pred, target, posidx, out,
                                            ws_num, ws_den, n);
    riou_finalize<<<1, 1, 0, stream>>>(ws_num, ws_den, out);
}